// Round 1
// baseline (91.578 us; speedup 1.0000x reference)
//
#include <hip/hip_runtime.h>
#include <stdint.h>

#define HSZ 2048
#define PRIME 500009u

typedef __attribute__((ext_vector_type(8))) short short8;
typedef __attribute__((ext_vector_type(4))) float f32x4;

// fp32 -> bf16 round-to-nearest-even (no NaN inputs here)
__device__ __forceinline__ short f2bf(float f) {
  union { float f; unsigned u; } v; v.f = f;
  unsigned u = v.u;
  unsigned r = (u + 0x7FFFu + ((u >> 16) & 1u)) >> 16;
  return (short)(unsigned short)r;
}

// load 8 consecutive fp32, convert to bf16x8 fragment
__device__ __forceinline__ short8 load8_bf(const float* __restrict__ p) {
  float4 a = *reinterpret_cast<const float4*>(p);
  float4 b = *reinterpret_cast<const float4*>(p + 4);
  short8 r;
  r[0] = f2bf(a.x); r[1] = f2bf(a.y); r[2] = f2bf(a.z); r[3] = f2bf(a.w);
  r[4] = f2bf(b.x); r[5] = f2bf(b.y); r[6] = f2bf(b.z); r[7] = f2bf(b.w);
  return r;
}

// -------- Kernel 1: hash + gather + (embvec @ Wh.T)  -> emb0[16384][32] f32 --------
// 512 blocks x 256 threads; 32 tokens/block.
__global__ __launch_bounds__(256) void emb0_kernel(
    const int* __restrict__ ids, const int* __restrict__ mapping,
    const unsigned* __restrict__ mult, const float* __restrict__ table,
    const float* __restrict__ Wh, float* __restrict__ emb0) {
  __shared__ __align__(16) short A_lds[32][264];  // [token][256 bf16 + pad8]
  __shared__ int idx_lds[256];                    // 32 tokens x 8 heads
  const int tid = threadIdx.x;
  const int t0 = blockIdx.x * 32;

  // 1) hash indices: thread = (token, head)
  {
    int t_loc = tid >> 3, head = tid & 7;
    int tg = t0 + t_loc;
    int b = tg >> 12, s = tg & 4095;
    const int* idb = ids + (b << 12);
    int s1 = s + 1 > 4095 ? 4095 : s + 1;
    int s2 = s + 2 > 4095 ? 4095 : s + 2;
    uint64_t c0 = (unsigned)mapping[idb[s]];
    uint64_t c1 = (unsigned)mapping[idb[s1]];
    uint64_t c2 = (unsigned)mapping[idb[s2]];
    int mb = head * 3;  // head = oi*4 + hd; multipliers row-major [2][4][3]
    uint64_t h = (c0 * (uint64_t)mult[mb]) ^ (c1 * (uint64_t)mult[mb + 1]);
    if (head >= 4) h ^= c2 * (uint64_t)mult[mb + 2];  // trigram order
    unsigned row = (unsigned)(h % PRIME) + (unsigned)head * PRIME;
    idx_lds[tid] = (int)row;
  }
  __syncthreads();

  // 2) gather table rows -> LDS as bf16 (8 lanes per 128B row, coalesced)
  #pragma unroll
  for (int p = 0; p < 8; ++p) {
    int r = p * 32 + (tid >> 3);
    int c4 = (tid & 7) * 4;
    long row = idx_lds[r];
    float4 v = *reinterpret_cast<const float4*>(table + row * 32 + c4);
    int tl = r >> 3, hd = r & 7;
    short* dst = &A_lds[tl][hd * 32 + c4];
    dst[0] = f2bf(v.x); dst[1] = f2bf(v.y); dst[2] = f2bf(v.z); dst[3] = f2bf(v.w);
  }
  __syncthreads();

  // 3) MFMA: wave = (token-tile, e-coltile); K=256 over 8 ksteps
  int wid = tid >> 6, lane = tid & 63;
  int tt = wid >> 1, e0 = (wid & 1) * 16;
  int l16 = lane & 15, q = lane >> 4;
  short8 Bf[8];
  #pragma unroll
  for (int ks = 0; ks < 8; ++ks)
    Bf[ks] = load8_bf(Wh + (size_t)(e0 + l16) * 256 + ks * 32 + q * 8);
  f32x4 acc = {0.f, 0.f, 0.f, 0.f};
  #pragma unroll
  for (int ks = 0; ks < 8; ++ks) {
    short8 a = *reinterpret_cast<const short8*>(&A_lds[tt * 16 + l16][ks * 32 + q * 8]);
    acc = __builtin_amdgcn_mfma_f32_16x16x32_bf16(a, Bf[ks], acc, 0, 0, 0);
  }
  // C layout (verified): col = lane&15, row = (lane>>4)*4 + j
  #pragma unroll
  for (int j = 0; j < 4; ++j) {
    int t = t0 + tt * 16 + q * 4 + j;
    emb0[(size_t)t * 32 + e0 + l16] = acc[j];
  }
}

// -------- Kernel 2: conv + gate(sigmoid(hidden@Wg.T)) * emb, then @ Wo.T --------
// 512 blocks x 256 threads; 32 tokens/block. Waves: (token-tile x K-half) for gate,
// h-split for output.
__global__ __launch_bounds__(256) void fuse_kernel(
    const float* __restrict__ hidden, const float* __restrict__ emb0,
    const float* __restrict__ cw, const float* __restrict__ cb,
    const float* __restrict__ Wg, const float* __restrict__ Wo,
    float* __restrict__ out) {
  __shared__ float emb_lds[32][33];
  __shared__ __align__(16) short ge_lds[32][40];
  __shared__ float accred[2][64][8];
  const int tid = threadIdx.x;
  const int t0 = blockIdx.x * 32;

  // conv preamble: emb[t,e] = cb[e] + sum_j cw[e,j] * emb0[t-3+j, e] (zero-pad at batch start)
  #pragma unroll
  for (int it = 0; it < 4; ++it) {
    int ii = it * 256 + tid;
    int tl = ii >> 5, e = ii & 31;
    int s = (t0 + tl) & 4095;
    float a = cb[e];
    #pragma unroll
    for (int j = 0; j < 4; ++j) {
      int sp = s - 3 + j;
      if (sp >= 0) a += cw[e * 4 + j] * emb0[(size_t)(t0 + tl - 3 + j) * 32 + e];
    }
    emb_lds[tl][e] = a;
  }

  int wid = tid >> 6, lane = tid & 63;
  int l16 = lane & 15, q = lane >> 4;
  int tt = wid & 1, kh = wid >> 1;

  // ---- phase A: gate matmul, K=2048 split across 2 waves (1024 each) ----
  f32x4 acc0 = {0, 0, 0, 0}, acc1 = {0, 0, 0, 0};
  const float* hrow = hidden + (size_t)(t0 + tt * 16 + l16) * HSZ + kh * 1024 + q * 8;
  const float* wg0 = Wg + (size_t)l16 * HSZ + kh * 1024 + q * 8;
  const float* wg1 = Wg + (size_t)(16 + l16) * HSZ + kh * 1024 + q * 8;
  for (int kc = 0; kc < 4; ++kc) {
    short8 B0[8], B1[8];
    #pragma unroll
    for (int ks = 0; ks < 8; ++ks) {
      B0[ks] = load8_bf(wg0 + kc * 256 + ks * 32);
      B1[ks] = load8_bf(wg1 + kc * 256 + ks * 32);
    }
    #pragma unroll
    for (int ks = 0; ks < 8; ++ks) {
      short8 a = load8_bf(hrow + kc * 256 + ks * 32);
      acc0 = __builtin_amdgcn_mfma_f32_16x16x32_bf16(a, B0[ks], acc0, 0, 0, 0);
      acc1 = __builtin_amdgcn_mfma_f32_16x16x32_bf16(a, B1[ks], acc1, 0, 0, 0);
    }
  }
  if (kh == 1) {
    #pragma unroll
    for (int j = 0; j < 4; ++j) {
      accred[tt][lane][j] = acc0[j];
      accred[tt][lane][4 + j] = acc1[j];
    }
  }
  __syncthreads();
  if (kh == 0) {
    #pragma unroll
    for (int j = 0; j < 4; ++j) {
      acc0[j] += accred[tt][lane][j];
      acc1[j] += accred[tt][lane][4 + j];
    }
    #pragma unroll
    for (int j = 0; j < 4; ++j) {
      int r = tt * 16 + q * 4 + j;
      float g0 = 1.f / (1.f + __expf(-acc0[j]));
      ge_lds[r][l16] = f2bf(g0 * emb_lds[r][l16]);
      float g1 = 1.f / (1.f + __expf(-acc1[j]));
      ge_lds[r][16 + l16] = f2bf(g1 * emb_lds[r][16 + l16]);
    }
  }
  __syncthreads();

  // ---- phase B: out[t,h] = ge @ Wo.T, one MFMA per (token-tile, h-tile), K=32 ----
  short8 Af0 = *reinterpret_cast<const short8*>(&ge_lds[l16][q * 8]);
  short8 Af1 = *reinterpret_cast<const short8*>(&ge_lds[16 + l16][q * 8]);
  int hbase = wid * 512;
  for (int ht = 0; ht < 32; ++ht) {
    int h0 = hbase + ht * 16;
    short8 bo = load8_bf(Wo + (size_t)(h0 + l16) * 32 + q * 8);
    f32x4 z = {0, 0, 0, 0};
    f32x4 o0 = __builtin_amdgcn_mfma_f32_16x16x32_bf16(Af0, bo, z, 0, 0, 0);
    f32x4 o1 = __builtin_amdgcn_mfma_f32_16x16x32_bf16(Af1, bo, z, 0, 0, 0);
    #pragma unroll
    for (int j = 0; j < 4; ++j) {
      out[(size_t)(t0 + q * 4 + j) * HSZ + h0 + l16] = o0[j];
      out[(size_t)(t0 + 16 + q * 4 + j) * HSZ + h0 + l16] = o1[j];
    }
  }
}

extern "C" void kernel_launch(void* const* d_in, const int* in_sizes, int n_in,
                              void* d_out, int out_size, void* d_ws, size_t ws_size,
                              hipStream_t stream) {
  const int* ids = (const int*)d_in[0];
  const float* hidden = (const float*)d_in[1];
  const int* mapping = (const int*)d_in[2];
  const unsigned* mult = (const unsigned*)d_in[3];  // int64 wrapped to int32; low 32 bits exact
  const float* table = (const float*)d_in[4];
  const float* cw = (const float*)d_in[5];
  const float* cb = (const float*)d_in[6];
  const float* Wh = (const float*)d_in[7];
  const float* Wg = (const float*)d_in[8];
  const float* Wo = (const float*)d_in[9];
  float* out = (float*)d_out;
  float* emb0 = (float*)d_ws;  // 16384 x 32 f32 = 2 MiB scratch

  emb0_kernel<<<512, 256, 0, stream>>>(ids, mapping, mult, table, Wh, emb0);
  fuse_kernel<<<512, 256, 0, stream>>>(hidden, emb0, cw, cb, Wg, Wo, out);
}